// Round 3
// baseline (212.467 us; speedup 1.0000x reference)
//
#include <hip/hip_runtime.h>
#include <math.h>
#include <stdint.h>

#define F_K 802816          // 64*112*112
#define KC 1024             // K-chunk per block
#define NB1 784             // F_K / KC
#define PRED_OFF 12845056
#define NORM_OFF 12845568   // PRED_OFF + 512

#define AS3 __attribute__((address_space(3)))
#define AS1 __attribute__((address_space(1)))

// async global->LDS, 16B per lane; dest = ldsbase + lane*16 (HW), src per-lane.
__device__ __forceinline__ void gload16(const float* gsrc, float* ldsbase) {
  __builtin_amdgcn_global_load_lds((const AS1 uint32_t*)gsrc, (AS3 uint32_t*)ldsbase, 16, 0, 0);
}

// ---------------- Kernel 1: split-K GEMM  part[blk] = x @ W1^T (k-chunk) --------
// 784 blocks x 256 thr, double-buffered 64-k tiles (72KB LDS, 2 blocks/CU).
// Wave w stages its quarter; counted vmcnt(9) keeps next tile's loads in
// flight across the barrier (T3 2-phase). Each thread: 4b x 8n acc tile.
// W tile column-swizzled: slot (n,c4) holds w[n][c4 ^ (n&7)] -> read col for
// kk4 is kk4 ^ (nl&7): conflict-free ds_read_b128.
__global__ __launch_bounds__(256) void k_gemm1(const float* __restrict__ x,
                                               const float* __restrict__ w1,
                                               float* __restrict__ part) {
  __shared__ __align__(16) float xs[2][16 * 64];     // 8 KB
  __shared__ __align__(16) float ws[2][128 * 64];    // 64 KB
  const int t = threadIdx.x;
  const int wave = t >> 6, lane = t & 63;
  const int nl = t & 15;
  const int bg = (t >> 4) & 3;
  const size_t k0 = (size_t)blockIdx.x * KC;

  // x staging: 256 f4 slots, one per thread. flat f4 = wave*64+lane.
  const int xf = wave * 64 + lane;
  const float* xsrc = x + (size_t)(xf >> 4) * F_K + k0 + 4 * (xf & 15);

  // w staging: 8 wave-calls; call cc covers f4 slots (wave*8+cc)*64 + lane.
  const float* wsrc[8];
#pragma unroll
  for (int cc = 0; cc < 8; ++cc) {
    int f = (wave * 8 + cc) * 64 + lane;
    int n = f >> 4, c = f & 15;
    wsrc[cc] = w1 + (size_t)n * F_K + k0 + 4 * (c ^ (n & 7));   // pre-swizzled col
  }

  float acc[4][8];
#pragma unroll
  for (int i = 0; i < 4; ++i)
#pragma unroll
    for (int j = 0; j < 8; ++j) acc[i][j] = 0.f;

  // prologue: stage tile 0 into buf 0
  gload16(xsrc, &xs[0][wave * 256]);
#pragma unroll
  for (int cc = 0; cc < 8; ++cc) gload16(wsrc[cc], &ws[0][wave * 2048 + cc * 256]);

  for (int kt = 0; kt < KC / 64; ++kt) {
    const int cur = kt & 1;
    if (kt < KC / 64 - 1) {
      const int nxt = cur ^ 1;
      gload16(xsrc + (kt + 1) * 64, &xs[nxt][wave * 256]);
#pragma unroll
      for (int cc = 0; cc < 8; ++cc)
        gload16(wsrc[cc] + (kt + 1) * 64, &ws[nxt][wave * 2048 + cc * 256]);
      asm volatile("s_waitcnt vmcnt(9)" ::: "memory");  // tile kt landed; kt+1 in flight
    } else {
      asm volatile("s_waitcnt vmcnt(0)" ::: "memory");
    }
    __builtin_amdgcn_s_barrier();
#pragma unroll
    for (int q = 0; q < 4; ++q) {
      const int kk4 = 4 * wave + q;
      float4 xv[4];
#pragma unroll
      for (int i = 0; i < 4; ++i)
        xv[i] = *reinterpret_cast<const float4*>(&xs[cur][(4 * bg + i) * 64 + 4 * kk4]);
      const int c = kk4 ^ (nl & 7);
#pragma unroll
      for (int j = 0; j < 8; ++j) {
        float4 wv = *reinterpret_cast<const float4*>(&ws[cur][(16 * j + nl) * 64 + 4 * c]);
#pragma unroll
        for (int i = 0; i < 4; ++i) {
          acc[i][j] += xv[i].x * wv.x;
          acc[i][j] += xv[i].y * wv.y;
          acc[i][j] += xv[i].z * wv.z;
          acc[i][j] += xv[i].w * wv.w;
        }
      }
    }
    __builtin_amdgcn_s_barrier();   // all reads of buf cur done before it's re-staged
  }

  // cross-wave K reduction (reuse ws[0] as red[4][2048])
  float* red = &ws[0][0];
#pragma unroll
  for (int i = 0; i < 4; ++i)
#pragma unroll
    for (int j = 0; j < 8; ++j)
      red[wave * 2048 + (4 * bg + i) * 128 + 16 * j + nl] = acc[i][j];
  __syncthreads();
  const int o8 = t * 8;
  float4 s0 = {0, 0, 0, 0}, s1 = {0, 0, 0, 0};
#pragma unroll
  for (int w = 0; w < 4; ++w) {
    float4 a = *reinterpret_cast<const float4*>(&red[w * 2048 + o8]);
    float4 b = *reinterpret_cast<const float4*>(&red[w * 2048 + o8 + 4]);
    s0.x += a.x; s0.y += a.y; s0.z += a.z; s0.w += a.w;
    s1.x += b.x; s1.y += b.y; s1.z += b.z; s1.w += b.w;
  }
  float* pp = part + (size_t)blockIdx.x * 2048 + o8;
  *reinterpret_cast<float4*>(pp) = s0;
  *reinterpret_cast<float4*>(pp + 4) = s1;
}

// ---------------- Kernel 2: 784-chunk reduce + heads + TPS solve ----------------
// 16 blocks x 256 threads. Phase 1: all threads reduce partials; phase 2:
// wave 0 only (single-wave LDS code, no barriers needed).
__global__ __launch_bounds__(256) void k_small(const float* __restrict__ part,
    const float* __restrict__ b1, const float* __restrict__ W2, const float* __restrict__ b2,
    const float* __restrict__ W3, const float* __restrict__ b3,
    const float* __restrict__ lmean, const float* __restrict__ scales,
    float* __restrict__ dout_pred, float* __restrict__ coef, float* __restrict__ norms) {
  const int b = blockIdx.x, t = threadIdx.x;
  __shared__ float o2[2][128];
  __shared__ float o[128], dflat[32], fl[32], A[19][22], farr[19], sol[19][2];

  // phase 1: reduce 784 partial chunks for this batch
  {
    const int n = t & 127, h = t >> 7;
    const float* p = part + (size_t)h * 2048 + b * 128 + n;
    float s = 0.f;
#pragma unroll 8
    for (int q = 0; q < 392; ++q) s += p[(size_t)q * 4096];
    o2[h][n] = s;
  }
  __syncthreads();
  if (t >= 64) return;

  const int lane = t;
  o[lane]      = o2[0][lane]      + o2[1][lane]      + b1[lane];
  o[lane + 64] = o2[0][lane + 64] + o2[1][lane + 64] + b1[lane + 64];

  // lanes 0..31: out@W2^T; lanes 32..63: out@W3^T
  const int j = lane & 31;
  const float* Wm = (lane < 32) ? (W2 + j * 128) : (W3 + j * 128);
  float acc = 0.f;
#pragma unroll 4
  for (int n = 0; n < 128; ++n) acc += o[n] * Wm[n];
  float other = __shfl(acc, j + 32);
  float sc = scales[b];
  float dspv = 0.f;
  if (lane < 32) {
    float predv = acc + b2[j] + lmean[j];
    dspv = (other + b3[j]) * sc;
    dout_pred[b * 32 + j] = predv;
    dflat[j] = predv + dspv;   // dst (flat y,x pairs)
    fl[j] = dspv;              // flows = dst - src
  }
  float s2 = (lane < 32) ? dspv * dspv : 0.f;
  for (int off = 32; off; off >>= 1) s2 += __shfl_xor(s2, off);
  if (lane == 0) norms[b] = sqrtf(s2);

  // build augmented TPS system A[19][19+2]
  for (int cell = lane; cell < 19 * 21; cell += 64) {
    int r = cell / 21, c = cell - (cell / 21) * 21;
    float v;
    if (r < 16) {
      if (c < 16) {
        float dy = dflat[2*r] - dflat[2*c], dx = dflat[2*r+1] - dflat[2*c+1];
        float d2 = dy * dy + dx * dx;
        v = 0.5f * d2 * logf(fmaxf(d2, 1e-10f));
        if (r == c) v += 1e-6f;
      } else if (c == 16) v = dflat[2*r];
      else if (c == 17) v = dflat[2*r+1];
      else if (c == 18) v = 1.0f;
      else if (c == 19) v = fl[2*r];
      else               v = fl[2*r+1];
    } else {
      int rr = r - 16;
      if (c < 16) v = (rr == 0) ? dflat[2*c] : (rr == 1) ? dflat[2*c+1] : 1.0f;
      else        v = 0.0f;
    }
    A[r][c] = v;
  }

  // Gaussian elimination with partial pivoting (single wave, lockstep)
  for (int k = 0; k < 19; ++k) {
    float av = (lane >= k && lane < 19) ? fabsf(A[lane][k]) : -1.0f;
    int idx = lane;
    for (int off = 32; off; off >>= 1) {
      float v2 = __shfl_xor(av, off);
      int  i2 = __shfl_xor(idx, off);
      if (v2 > av) { av = v2; idx = i2; }
    }
    idx = __shfl(idx, 0);   // consistent pivot across lanes
    if (idx != k && lane < 21) {
      float tmp = A[k][lane]; A[k][lane] = A[idx][lane]; A[idx][lane] = tmp;
    }
    float invp = 1.0f / A[k][k];
    if (lane < 19) farr[lane] = (lane > k) ? A[lane][k] * invp : 0.0f;
    int nr = 18 - k, nc = 20 - k;
    for (int cell = lane; cell < nr * nc; cell += 64) {
      int i = k + 1 + cell / nc, jj = k + 1 + cell % nc;
      A[i][jj] -= farr[i] * A[k][jj];
    }
  }
  // back substitution (2 rhs columns in parallel)
  for (int k = 18; k >= 0; --k) {
    if (lane < 2) sol[k][lane] = A[k][19 + lane] / A[k][k];
    if (lane < 2 * k) {
      int i = lane >> 1, c = lane & 1;
      A[i][19 + c] -= A[i][k] * sol[k][c];
    }
  }
  // store coefficients: [0..31]=w, [32..37]=v, [38..69]=dst
  float* cf = coef + b * 80;
  if (lane < 32) { cf[lane] = sol[lane >> 1][lane & 1]; cf[38 + lane] = dflat[lane]; }
  else if (lane < 38) cf[lane] = sol[16 + ((lane - 32) >> 1)][(lane - 32) & 1];
}

// ---------------- Kernel 3: dense TPS flow + bilinear warp + NHWC->NCHW ----------------
__global__ __launch_bounds__(256) void k_warp(const float* __restrict__ img,
                                              const float* __restrict__ coef,
                                              const float* __restrict__ norms,
                                              float* __restrict__ out) {
  const int bid = blockIdx.x;
  const int b = bid / 112, y = bid - (bid / 112) * 112;
  const int t = threadIdx.x;
  __shared__ float qy[112], qx[112];
  __shared__ float cw[32], cv[6], cd[32];
  __shared__ float tile[64][113];   // pad 113 -> conflict-free transposed access

  if (bid == 0 && t == 0) {         // finalize landmarks_norm
    float s = 0.f;
    for (int i = 0; i < 16; ++i) s += norms[i];
    out[NORM_OFF] = s * (1.0f / 16.0f);
  }
  const float* cf = coef + b * 80;
  if (t < 70) {
    float v = cf[t];
    if (t < 32) cw[t] = v;
    else if (t < 38) cv[t - 32] = v;
    else cd[t - 38] = v;
  }
  __syncthreads();

  // phase A: per-pixel TPS flow -> query coords
  if (t < 112) {
    float fy = (float)y, fx = (float)t;
    float s0 = cv[0] * fy + cv[2] * fx + cv[4];
    float s1 = cv[1] * fy + cv[3] * fx + cv[5];
#pragma unroll
    for (int i = 0; i < 16; ++i) {
      float dy = fy - cd[2 * i], dx = fx - cd[2 * i + 1];
      float d2 = dy * dy + dx * dx;
      float ph = 0.5f * d2 * logf(fmaxf(d2, 1e-10f));
      s0 += ph * cw[2 * i];
      s1 += ph * cw[2 * i + 1];
    }
    qy[t] = fy - s0;
    qx[t] = fx - s1;
  }
  __syncthreads();

  // phase B: bilinear gather, lane = channel (coalesced 256B per neighbor)
  const int wave = t >> 6, lane = t & 63;
#pragma unroll 4
  for (int p = 0; p < 28; ++p) {
    int xx = wave * 28 + p;
    float fy = qy[xx], fx = qx[xx];
    float y0f = fminf(fmaxf(floorf(fy), 0.f), 110.f);
    float x0f = fminf(fmaxf(floorf(fx), 0.f), 110.f);
    float ay = fminf(fmaxf(fy - y0f, 0.f), 1.f);
    float ax = fminf(fmaxf(fx - x0f, 0.f), 1.f);
    int y0 = (int)y0f, x0 = (int)x0f;
    const float* p00 = img + (((size_t)(b * 112 + y0) * 112 + x0) * 64) + lane;
    float v00 = p00[0], v01 = p00[64];
    float v10 = p00[112 * 64], v11 = p00[112 * 64 + 64];
    float top = v00 * (1.f - ax) + v01 * ax;
    float bot = v10 * (1.f - ax) + v11 * ax;
    tile[lane][xx] = top * (1.f - ay) + bot * ay;
  }
  __syncthreads();

  // phase C: coalesced NCHW write
  float* ob = out + (size_t)b * 64 * 12544 + y * 112;
  for (int i = 0; i < 28; ++i) {
    int idx = i * 256 + t;           // < 7168
    int c = idx / 112, xx = idx - c * 112;
    ob[(size_t)c * 12544 + xx] = tile[c][xx];
  }
}

extern "C" void kernel_launch(void* const* d_in, const int* in_sizes, int n_in,
                              void* d_out, int out_size, void* d_ws, size_t ws_size,
                              hipStream_t stream) {
  const float* x      = (const float*)d_in[0];
  const float* img    = (const float*)d_in[1];
  const float* scales = (const float*)d_in[2];
  const float* W1     = (const float*)d_in[3];
  const float* b1     = (const float*)d_in[4];
  const float* W2     = (const float*)d_in[5];
  const float* b2     = (const float*)d_in[6];
  const float* W3     = (const float*)d_in[7];
  const float* b3     = (const float*)d_in[8];
  const float* lmean  = (const float*)d_in[9];
  float* out = (float*)d_out;
  float* ws  = (float*)d_ws;

  float* P1   = ws;                       // 784*2048 floats
  float* COEF = P1 + (size_t)NB1 * 2048;  // 16*80
  float* NORM = COEF + 16 * 80;           // 16

  k_gemm1<<<NB1, 256, 0, stream>>>(x, W1, P1);
  k_small<<<16, 256, 0, stream>>>(P1, b1, W2, b2, W3, b3, lmean, scales,
                                  out + PRED_OFF, COEF, NORM);
  k_warp <<<16 * 112, 256, 0, stream>>>(img, COEF, NORM, out);
}

// Round 4
// 177.657 us; speedup vs baseline: 1.1959x; 1.1959x over previous
//
#include <hip/hip_runtime.h>
#include <math.h>
#include <stdint.h>

#define F_K 802816          // 64*112*112
#define KC 1024             // K-chunk per block
#define NB1 784             // F_K / KC
#define PRED_OFF 12845056
#define NORM_OFF 12845568   // PRED_OFF + 512

#define AS3 __attribute__((address_space(3)))
#define AS1 __attribute__((address_space(1)))

// async global->LDS, 16B per lane; LDS dest = base + lane*16 (HW), src per-lane.
__device__ __forceinline__ void gload16(const float* gsrc, float* ldsbase) {
  __builtin_amdgcn_global_load_lds((const AS1 uint32_t*)gsrc, (AS3 uint32_t*)ldsbase, 16, 0, 0);
}

// ---------------- Kernel 1: split-K GEMM  part[blk] = x @ W1^T (k-chunk) --------
// 784 blocks x 256 thr, 36KB LDS (4 blocks/CU). BARRIER-FREE k-loop: wave w
// owns k-slice [16w,16w+16) of each 64-k tile, stages it into wave-private LDS
// and waits only on its own vmcnt -> 16 independent self-paced streams per CU.
// LDS cell layout (16B cells): cell(row,q) = row*4 + ((q + (row>>1)) & 3);
// inverse rotation applied to the GLOBAL source col (linear LDS dest).
// W reads: 2-way bank aliasing (free); x reads: pure broadcast per 16-lane phase.
__global__ __launch_bounds__(256) void k_gemm1(const float* __restrict__ x,
                                               const float* __restrict__ w1,
                                               float* __restrict__ part) {
  __shared__ __align__(16) float xs[256 * 4];      // 4 KB  (wave w: cells [64w,64w+64))
  __shared__ __align__(16) float ws[2048 * 4];     // 32 KB (wave w: cells [512w,512w+512))
  const int t = threadIdx.x;
  const int wave = t >> 6, lane = t & 63;
  const int nl = t & 15;
  const int bg = (t >> 4) & 3;
  const size_t k0 = (size_t)blockIdx.x * KC;

  // ---- staging source addresses (per-lane, inverse-rotated column) ----
  // W: 8 calls; call cc covers cells cc*64+lane of the wave's 512-cell region.
  const float* wsrc[8];
#pragma unroll
  for (int cc = 0; cc < 8; ++cc) {
    int flat = cc * 64 + lane;          // 0..511
    int n = flat >> 2, tau = flat & 3;
    int q = (tau - (n >> 1)) & 3;       // source col within wave slice
    wsrc[cc] = w1 + (size_t)n * F_K + k0 + 16 * wave + 4 * q;
  }
  // x: 1 call; cells lane of the wave's 64-cell region.
  const float* xsrc;
  {
    int b = lane >> 2, tau = lane & 3;
    int q = (tau - (b >> 1)) & 3;
    xsrc = x + (size_t)b * F_K + k0 + 16 * wave + 4 * q;
  }
  float* xbase = xs + wave * 256;       // 64 cells * 4 floats
  float* wbase = ws + wave * 2048;      // 512 cells * 4 floats

  float acc[4][8];
#pragma unroll
  for (int i = 0; i < 4; ++i)
#pragma unroll
    for (int j = 0; j < 8; ++j) acc[i][j] = 0.f;

  for (int kt = 0; kt < KC / 64; ++kt) {
    // no pending ds ops when DMA writes land (wave-local ordering)
    asm volatile("s_waitcnt lgkmcnt(0)" ::: "memory");
    gload16(xsrc + kt * 64, xbase);
#pragma unroll
    for (int cc = 0; cc < 8; ++cc) gload16(wsrc[cc] + kt * 64, wbase + cc * 256);
    asm volatile("s_waitcnt vmcnt(0)" ::: "memory");
    __builtin_amdgcn_sched_barrier(0);
#pragma unroll
    for (int q = 0; q < 4; ++q) {
      float4 xv[4];
#pragma unroll
      for (int i = 0; i < 4; ++i) {
        int b = 4 * bg + i;
        int tx = (q + (b >> 1)) & 3;
        xv[i] = *reinterpret_cast<const float4*>(&xbase[b * 16 + 4 * tx]);
      }
      const int tw = (q + (nl >> 1)) & 3;   // 8j contributes 0 mod 4
#pragma unroll
      for (int j = 0; j < 8; ++j) {
        float4 wv = *reinterpret_cast<const float4*>(&wbase[(16 * j + nl) * 16 + 4 * tw]);
#pragma unroll
        for (int i = 0; i < 4; ++i) {
          acc[i][j] += xv[i].x * wv.x;
          acc[i][j] += xv[i].y * wv.y;
          acc[i][j] += xv[i].z * wv.z;
          acc[i][j] += xv[i].w * wv.w;
        }
      }
    }
  }

  // cross-wave K reduction (reuse ws as red[4][2048])
  __syncthreads();
  float* red = ws;
#pragma unroll
  for (int i = 0; i < 4; ++i)
#pragma unroll
    for (int j = 0; j < 8; ++j)
      red[wave * 2048 + (4 * bg + i) * 128 + 16 * j + nl] = acc[i][j];
  __syncthreads();
  const int o8 = t * 8;
  float4 s0 = {0, 0, 0, 0}, s1 = {0, 0, 0, 0};
#pragma unroll
  for (int w = 0; w < 4; ++w) {
    float4 a = *reinterpret_cast<const float4*>(&red[w * 2048 + o8]);
    float4 b = *reinterpret_cast<const float4*>(&red[w * 2048 + o8 + 4]);
    s0.x += a.x; s0.y += a.y; s0.z += a.z; s0.w += a.w;
    s1.x += b.x; s1.y += b.y; s1.z += b.z; s1.w += b.w;
  }
  float* pp = part + (size_t)blockIdx.x * 2048 + o8;
  *reinterpret_cast<float4*>(pp) = s0;
  *reinterpret_cast<float4*>(pp + 4) = s1;
}

// ---------------- Kernel 2a: reduce 784 partials -> 16 partials ----------------
__global__ __launch_bounds__(256) void k_red(const float* __restrict__ part,
                                             float* __restrict__ p2) {
  int pc = blockIdx.x >> 3, ib = blockIdx.x & 7;
  int idx = ib * 256 + threadIdx.x;               // 0..2047
  const float* p = part + (size_t)pc * 49 * 2048 + idx;
  float s = 0.f;
  for (int q = 0; q < 49; ++q) s += p[(size_t)q * 2048];
  p2[pc * 2048 + idx] = s;
}

// ---------------- Kernel 2b: small heads + TPS solve (1 wave / batch) ----------------
__global__ __launch_bounds__(64) void k_small(const float* __restrict__ p2,
    const float* __restrict__ b1, const float* __restrict__ W2, const float* __restrict__ b2,
    const float* __restrict__ W3, const float* __restrict__ b3,
    const float* __restrict__ lmean, const float* __restrict__ scales,
    float* __restrict__ dout_pred, float* __restrict__ coef, float* __restrict__ norms) {
  const int b = blockIdx.x, lane = threadIdx.x;
  __shared__ float o[128], dflat[32], fl[32], A[19][22], farr[19], sol[19][2];

  // final K-reduction + b1
  for (int h = 0; h < 2; ++h) {
    int n = lane + 64 * h;
    float s = b1[n];
    for (int pc = 0; pc < 16; ++pc) s += p2[pc * 2048 + b * 128 + n];
    o[n] = s;
  }
  __syncthreads();

  // lanes 0..31: out@W2^T; lanes 32..63: out@W3^T
  const int j = lane & 31;
  const float* Wm = (lane < 32) ? (W2 + j * 128) : (W3 + j * 128);
  float acc = 0.f;
#pragma unroll 4
  for (int n = 0; n < 128; ++n) acc += o[n] * Wm[n];
  float other = __shfl(acc, j + 32);
  float sc = scales[b];
  float dspv = 0.f;
  if (lane < 32) {
    float predv = acc + b2[j] + lmean[j];
    dspv = (other + b3[j]) * sc;
    dout_pred[b * 32 + j] = predv;
    dflat[j] = predv + dspv;   // dst (flat y,x pairs)
    fl[j] = dspv;              // flows = dst - src
  }
  float s2 = (lane < 32) ? dspv * dspv : 0.f;
  for (int off = 32; off; off >>= 1) s2 += __shfl_xor(s2, off);
  if (lane == 0) norms[b] = sqrtf(s2);
  __syncthreads();

  // build augmented TPS system A[19][19+2]
  for (int cell = lane; cell < 19 * 21; cell += 64) {
    int r = cell / 21, c = cell - (cell / 21) * 21;
    float v;
    if (r < 16) {
      if (c < 16) {
        float dy = dflat[2*r] - dflat[2*c], dx = dflat[2*r+1] - dflat[2*c+1];
        float d2 = dy * dy + dx * dx;
        v = 0.5f * d2 * logf(fmaxf(d2, 1e-10f));
        if (r == c) v += 1e-6f;
      } else if (c == 16) v = dflat[2*r];
      else if (c == 17) v = dflat[2*r+1];
      else if (c == 18) v = 1.0f;
      else if (c == 19) v = fl[2*r];
      else               v = fl[2*r+1];
    } else {
      int rr = r - 16;
      if (c < 16) v = (rr == 0) ? dflat[2*c] : (rr == 1) ? dflat[2*c+1] : 1.0f;
      else        v = 0.0f;
    }
    A[r][c] = v;
  }
  __syncthreads();

  // Gaussian elimination with partial pivoting
  for (int k = 0; k < 19; ++k) {
    float av = (lane >= k && lane < 19) ? fabsf(A[lane][k]) : -1.0f;
    int idx = lane;
    for (int off = 32; off; off >>= 1) {
      float v2 = __shfl_xor(av, off);
      int  i2 = __shfl_xor(idx, off);
      if (v2 > av) { av = v2; idx = i2; }
    }
    idx = __shfl(idx, 0);   // consistent pivot across lanes
    if (idx != k && lane < 21) {
      float tmp = A[k][lane]; A[k][lane] = A[idx][lane]; A[idx][lane] = tmp;
    }
    __syncthreads();
    float invp = 1.0f / A[k][k];
    if (lane < 19) farr[lane] = (lane > k) ? A[lane][k] * invp : 0.0f;
    __syncthreads();
    int nr = 18 - k, nc = 20 - k;
    for (int cell = lane; cell < nr * nc; cell += 64) {
      int i = k + 1 + cell / nc, jj = k + 1 + cell % nc;
      A[i][jj] -= farr[i] * A[k][jj];
    }
    __syncthreads();
  }
  // back substitution (2 rhs columns in parallel)
  for (int k = 18; k >= 0; --k) {
    if (lane < 2) sol[k][lane] = A[k][19 + lane] / A[k][k];
    __syncthreads();
    if (lane < 2 * k) {
      int i = lane >> 1, c = lane & 1;
      A[i][19 + c] -= A[i][k] * sol[k][c];
    }
    __syncthreads();
  }
  // store coefficients: [0..31]=w, [32..37]=v, [38..69]=dst
  float* cf = coef + b * 80;
  if (lane < 32) { cf[lane] = sol[lane >> 1][lane & 1]; cf[38 + lane] = dflat[lane]; }
  else if (lane < 38) cf[lane] = sol[16 + ((lane - 32) >> 1)][(lane - 32) & 1];
}

// ---------------- Kernel 3: dense TPS flow + bilinear warp + NHWC->NCHW ----------------
__global__ __launch_bounds__(256) void k_warp(const float* __restrict__ img,
                                              const float* __restrict__ coef,
                                              const float* __restrict__ norms,
                                              float* __restrict__ out) {
  const int bid = blockIdx.x;
  const int b = bid / 112, y = bid - (bid / 112) * 112;
  const int t = threadIdx.x;
  __shared__ float qy[112], qx[112];
  __shared__ float cw[32], cv[6], cd[32];
  __shared__ float tile[64][113];   // pad 113 -> conflict-free transposed access

  if (bid == 0 && t == 0) {         // finalize landmarks_norm
    float s = 0.f;
    for (int i = 0; i < 16; ++i) s += norms[i];
    out[NORM_OFF] = s * (1.0f / 16.0f);
  }
  const float* cf = coef + b * 80;
  if (t < 70) {
    float v = cf[t];
    if (t < 32) cw[t] = v;
    else if (t < 38) cv[t - 32] = v;
    else cd[t - 38] = v;
  }
  __syncthreads();

  // phase A: per-pixel TPS flow -> query coords
  if (t < 112) {
    float fy = (float)y, fx = (float)t;
    float s0 = cv[0] * fy + cv[2] * fx + cv[4];
    float s1 = cv[1] * fy + cv[3] * fx + cv[5];
#pragma unroll
    for (int i = 0; i < 16; ++i) {
      float dy = fy - cd[2 * i], dx = fx - cd[2 * i + 1];
      float d2 = dy * dy + dx * dx;
      float ph = 0.5f * d2 * logf(fmaxf(d2, 1e-10f));
      s0 += ph * cw[2 * i];
      s1 += ph * cw[2 * i + 1];
    }
    qy[t] = fy - s0;
    qx[t] = fx - s1;
  }
  __syncthreads();

  // phase B: bilinear gather, lane = channel (coalesced 256B per neighbor)
  const int wave = t >> 6, lane = t & 63;
#pragma unroll 4
  for (int p = 0; p < 28; ++p) {
    int xx = wave * 28 + p;
    float fy = qy[xx], fx = qx[xx];
    float y0f = fminf(fmaxf(floorf(fy), 0.f), 110.f);
    float x0f = fminf(fmaxf(floorf(fx), 0.f), 110.f);
    float ay = fminf(fmaxf(fy - y0f, 0.f), 1.f);
    float ax = fminf(fmaxf(fx - x0f, 0.f), 1.f);
    int y0 = (int)y0f, x0 = (int)x0f;
    const float* p00 = img + (((size_t)(b * 112 + y0) * 112 + x0) * 64) + lane;
    float v00 = p00[0], v01 = p00[64];
    float v10 = p00[112 * 64], v11 = p00[112 * 64 + 64];
    float top = v00 * (1.f - ax) + v01 * ax;
    float bot = v10 * (1.f - ax) + v11 * ax;
    tile[lane][xx] = top * (1.f - ay) + bot * ay;
  }
  __syncthreads();

  // phase C: coalesced NCHW write
  float* ob = out + (size_t)b * 64 * 12544 + y * 112;
  for (int i = 0; i < 28; ++i) {
    int idx = i * 256 + t;           // < 7168
    int c = idx / 112, xx = idx - c * 112;
    ob[(size_t)c * 12544 + xx] = tile[c][xx];
  }
}

extern "C" void kernel_launch(void* const* d_in, const int* in_sizes, int n_in,
                              void* d_out, int out_size, void* d_ws, size_t ws_size,
                              hipStream_t stream) {
  const float* x      = (const float*)d_in[0];
  const float* img    = (const float*)d_in[1];
  const float* scales = (const float*)d_in[2];
  const float* W1     = (const float*)d_in[3];
  const float* b1     = (const float*)d_in[4];
  const float* W2     = (const float*)d_in[5];
  const float* b2     = (const float*)d_in[6];
  const float* W3     = (const float*)d_in[7];
  const float* b3     = (const float*)d_in[8];
  const float* lmean  = (const float*)d_in[9];
  float* out = (float*)d_out;
  float* ws  = (float*)d_ws;

  float* P1   = ws;                       // 784*2048 floats
  float* P2   = P1 + (size_t)NB1 * 2048;  // 16*2048
  float* COEF = P2 + 16 * 2048;           // 16*80
  float* NORM = COEF + 16 * 80;           // 16

  k_gemm1<<<NB1, 256, 0, stream>>>(x, W1, P1);
  k_red  <<<128, 256, 0, stream>>>(P1, P2);
  k_small<<<16, 64, 0, stream>>>(P2, b1, W2, b2, W3, b3, lmean, scales,
                                 out + PRED_OFF, COEF, NORM);
  k_warp <<<16 * 112, 256, 0, stream>>>(img, COEF, NORM, out);
}